// Round 3
// baseline (26.327 us; speedup 1.0000x reference)
//
#include <hip/hip_runtime.h>

// CenterLoss: loss = mean_b clip(||x_b - centers[labels[b]]||^2, 1e-12, 1e12)
//             + (C-1)*1e-12   (faithful replication of clipping the masked zeros)
//
// x:       (8192, 2048) f32
// labels:  (8192,)      int
// centers: (4096, 2048) f32
// out:     scalar f32
//
// Stage 1: one wave per sample; ALL 16 float4 loads issued before any compute
//          (explicitly-live arrays -> compiler can't register-minimize the MLP
//          away; R1 showed VGPR_Count=12, i.e. serialized loads).
//          Each wave stores its clipped sample directly -> no LDS, no barrier.
// Stage 2: single block reduces the 8192 per-sample values (32 KB, L2-hot).

#define BATCH 8192
#define FEAT  2048
#define NCLS  4096
#define BLK   256
#define WAVES_PER_BLK (BLK / 64)              // 4
#define NBLK (BATCH / WAVES_PER_BLK)          // 2048

__global__ void __launch_bounds__(BLK)
cl_dist(const float* __restrict__ x,
        const int* __restrict__ labels,
        const float* __restrict__ centers,
        float* __restrict__ part) {
    const int tid  = threadIdx.x;
    const int wid  = tid >> 6;
    const int lane = tid & 63;
    const int b    = blockIdx.x * WAVES_PER_BLK + wid;   // sample for this wave

    const int lbl = labels[b];                           // wave-uniform -> s_load

    const float4* __restrict__ xr =
        reinterpret_cast<const float4*>(x + (size_t)b * FEAT);
    const float4* __restrict__ cr =
        reinterpret_cast<const float4*>(centers + (size_t)lbl * FEAT);

    // Issue all 16 loads before any use: 16 outstanding 16B loads per lane.
    float4 xv[8], cv[8];
#pragma unroll
    for (int j = 0; j < 8; ++j) xv[j] = xr[lane + j * 64];
#pragma unroll
    for (int j = 0; j < 8; ++j) cv[j] = cr[lane + j * 64];

    float acc0 = 0.0f, acc1 = 0.0f;
#pragma unroll
    for (int j = 0; j < 8; ++j) {
        const float d0 = xv[j].x - cv[j].x;
        const float d1 = xv[j].y - cv[j].y;
        const float d2 = xv[j].z - cv[j].z;
        const float d3 = xv[j].w - cv[j].w;
        acc0 += d0 * d0 + d1 * d1;
        acc1 += d2 * d2 + d3 * d3;
    }
    float acc = acc0 + acc1;

    // wave (64-lane) reduction
#pragma unroll
    for (int off = 32; off > 0; off >>= 1)
        acc += __shfl_down(acc, off, 64);

    if (lane == 0) {
        // per-sample clip; direct per-wave store (no LDS, no __syncthreads)
        part[b] = fminf(fmaxf(acc, 1e-12f), 1e12f);
    }
}

__global__ void __launch_bounds__(BLK)
cl_final(const float* __restrict__ part, float* __restrict__ out) {
    const int tid = threadIdx.x;
    const float4* __restrict__ pr = reinterpret_cast<const float4*>(part);

    float acc = 0.0f;
#pragma unroll
    for (int j = 0; j < BATCH / 4 / BLK; ++j) {          // 8 iterations
        const float4 v = pr[tid + j * BLK];
        acc += (v.x + v.y) + (v.z + v.w);
    }

#pragma unroll
    for (int off = 32; off > 0; off >>= 1)
        acc += __shfl_down(acc, off, 64);

    __shared__ float s[BLK / 64];
    const int wid  = tid >> 6;
    const int lane = tid & 63;
    if (lane == 0) s[wid] = acc;
    __syncthreads();

    if (tid == 0) {
        const float total = s[0] + s[1] + s[2] + s[3];
        // masked-zero entries: (BATCH*NCLS - BATCH) * 1e-12 / BATCH
        out[0] = total / (float)BATCH + (float)(NCLS - 1) * 1e-12f;
    }
}

extern "C" void kernel_launch(void* const* d_in, const int* in_sizes, int n_in,
                              void* d_out, int out_size, void* d_ws, size_t ws_size,
                              hipStream_t stream) {
    const float* x       = (const float*)d_in[0];
    const int*   labels  = (const int*)d_in[1];
    const float* centers = (const float*)d_in[2];
    float* out  = (float*)d_out;
    float* part = (float*)d_ws;   // 8192 floats, fully overwritten every call

    cl_dist<<<NBLK, BLK, 0, stream>>>(x, labels, centers, part);
    cl_final<<<1, BLK, 0, stream>>>(part, out);
}

// Round 4
// 25.644 us; speedup vs baseline: 1.0266x; 1.0266x over previous
//
#include <hip/hip_runtime.h>

// CenterLoss: loss = mean_b clip(||x_b - centers[labels[b]]||^2, 1e-12, 1e12)
//             + (C-1)*1e-12   (faithful replication of clipping the masked zeros)
//
// x:       (8192, 2048) f32
// labels:  (8192,)      int
// centers: (4096, 2048) f32
// out:     scalar f32
//
// Stage 1: 512 blocks x 4 waves = 2048 long-lived waves; each wave streams 4
//          consecutive samples with a register double-buffer pipeline (loads
//          for sample s+1 in flight while computing sample s). Named buffers
//          (xa/ca, xb/cb) keep all indexing static -> no scratch.
// Stage 2: single block reduces the 8192 per-sample values (32 KB, L2-hot).

#define BATCH 8192
#define FEAT  2048
#define NCLS  4096
#define BLK   256
#define WAVES_PER_BLK (BLK / 64)                 // 4
#define NBLK 512
#define NWAVE (NBLK * WAVES_PER_BLK)             // 2048
#define SPW (BATCH / NWAVE)                      // 4 samples per wave

__global__ void __launch_bounds__(BLK)
cl_dist(const float* __restrict__ x,
        const int* __restrict__ labels,
        const float* __restrict__ centers,
        float* __restrict__ part) {
    const int tid  = threadIdx.x;
    const int wid  = tid >> 6;
    const int lane = tid & 63;
    const int gw   = blockIdx.x * WAVES_PER_BLK + wid;   // 0..2047
    const int b0   = gw * SPW;                           // first of 4 samples

    float4 xa[8], ca[8], xb[8], cb[8];

#define ISSUE(XBUF, CBUF, S)                                                   \
    {                                                                          \
        const float4* __restrict__ xr =                                        \
            reinterpret_cast<const float4*>(x + (size_t)(b0 + (S)) * FEAT);    \
        const int lbl = labels[b0 + (S)];                                      \
        const float4* __restrict__ cr =                                        \
            reinterpret_cast<const float4*>(centers + (size_t)lbl * FEAT);     \
        _Pragma("unroll")                                                      \
        for (int j = 0; j < 8; ++j) XBUF[j] = xr[lane + j * 64];               \
        _Pragma("unroll")                                                      \
        for (int j = 0; j < 8; ++j) CBUF[j] = cr[lane + j * 64];               \
    }

#define COMPUTE(XBUF, CBUF, S)                                                 \
    {                                                                          \
        float a0 = 0.0f, a1 = 0.0f;                                            \
        _Pragma("unroll")                                                      \
        for (int j = 0; j < 8; ++j) {                                          \
            const float d0 = XBUF[j].x - CBUF[j].x;                            \
            const float d1 = XBUF[j].y - CBUF[j].y;                            \
            const float d2 = XBUF[j].z - CBUF[j].z;                            \
            const float d3 = XBUF[j].w - CBUF[j].w;                            \
            a0 += d0 * d0 + d1 * d1;                                           \
            a1 += d2 * d2 + d3 * d3;                                           \
        }                                                                      \
        float acc = a0 + a1;                                                   \
        _Pragma("unroll")                                                      \
        for (int off = 32; off > 0; off >>= 1)                                 \
            acc += __shfl_down(acc, off, 64);                                  \
        if (lane == 0)                                                         \
            part[b0 + (S)] = fminf(fmaxf(acc, 1e-12f), 1e12f);                 \
    }

    // software pipeline over 4 samples, depth 2
    ISSUE(xa, ca, 0);
    ISSUE(xb, cb, 1);
    COMPUTE(xa, ca, 0);      // waits only on buf A (WAR deps keep order)
    ISSUE(xa, ca, 2);
    COMPUTE(xb, cb, 1);
    ISSUE(xb, cb, 3);
    COMPUTE(xa, ca, 2);
    COMPUTE(xb, cb, 3);

#undef ISSUE
#undef COMPUTE
}

__global__ void __launch_bounds__(BLK)
cl_final(const float* __restrict__ part, float* __restrict__ out) {
    const int tid = threadIdx.x;
    const float4* __restrict__ pr = reinterpret_cast<const float4*>(part);

    float acc = 0.0f;
#pragma unroll
    for (int j = 0; j < BATCH / 4 / BLK; ++j) {          // 8 iterations
        const float4 v = pr[tid + j * BLK];
        acc += (v.x + v.y) + (v.z + v.w);
    }

#pragma unroll
    for (int off = 32; off > 0; off >>= 1)
        acc += __shfl_down(acc, off, 64);

    __shared__ float s[BLK / 64];
    const int wid  = tid >> 6;
    const int lane = tid & 63;
    if (lane == 0) s[wid] = acc;
    __syncthreads();

    if (tid == 0) {
        const float total = s[0] + s[1] + s[2] + s[3];
        // masked-zero entries: (BATCH*NCLS - BATCH) * 1e-12 / BATCH
        out[0] = total / (float)BATCH + (float)(NCLS - 1) * 1e-12f;
    }
}

extern "C" void kernel_launch(void* const* d_in, const int* in_sizes, int n_in,
                              void* d_out, int out_size, void* d_ws, size_t ws_size,
                              hipStream_t stream) {
    const float* x       = (const float*)d_in[0];
    const int*   labels  = (const int*)d_in[1];
    const float* centers = (const float*)d_in[2];
    float* out  = (float*)d_out;
    float* part = (float*)d_ws;   // 8192 floats, fully overwritten every call

    cl_dist<<<NBLK, BLK, 0, stream>>>(x, labels, centers, part);
    cl_final<<<1, BLK, 0, stream>>>(part, out);
}